// Round 2
// baseline (797.091 us; speedup 1.0000x reference)
//
#include <hip/hip_runtime.h>

// GNN_layer: N=4, A_IN=8, A_OUT=16, X=64, n=1024.
// Inputs: float32. Outputs: float32 (reference output dtype).
// Decomposition:
//   At[b,i,j,s] = Base + pairA[i,s] + pairA[j,s] + constA[s],  Base = sum_c A[b,c,i,j] W1[c,s]
//   einsum factors through G[b,c,i,t] = A[b,c] @ X2t (MFMA, A cast to bf16 in-reg).
// THIS VERSION (round 2): occupancy/parallelism pass.
//  - k_fusedT: 512 blocks (2/CU, 16 waves/CU). Each i-tile is split across two
//    co-resident blocks by t-half (disjoint G writes) and s-half (disjoint At writes).
//    out1 moved back to a separate k_out (128 blocks).
//  - k_small (8 blocks) split into k_H (68 blocks, vectorized) + k_small2 (132 blocks).
//  - X column sums moved from k_batchstats (4 blocks) into 64 extra k_rowstats blocks.
//  - H/s2/Xpart overlay G's workspace region (consumed before G is written): ws unchanged.

#define NB 4
#define CI 8
#define SO 16
#define XD 64
#define NN 1024

typedef unsigned short u16;
typedef unsigned int u32;
typedef float f32x4 __attribute__((ext_vector_type(4)));
typedef short bf16x8 __attribute__((ext_vector_type(8)));

// ---- workspace layout (bytes), total 0x660000 = 6.7 MB ----
#define WS_MOC    0x000000u  // f32[4*8*1024]
#define WS_DP     0x020000u  // f32[4*8*1024]
#define WS_CONSTA 0x043000u  // f32[4*16]
#define WS_CX1    0x044000u  // f32[4*64]
#define WS_CX2    0x045000u  // f32[4*64]
#define WS_K1     0x048000u  // f32[4*16*64]
#define WS_C2     0x04C000u  // f32[4*64]
#define WS_PAIRA  0x050000u  // f32[4*1024*16]
#define WS_PAIRAT 0x090000u  // f32[4*16*1024]
#define WS_X1T    0x0D0000u  // f32[4*1024*64]
#define WS_X2TT   0x1D0000u  // bf16[4*64*1024]
#define WS_WGT    0x250000u  // bf16[64*512]
#define WS_G      0x260000u  // bf16[4*8*1024*64] (4 MB)
// Overlays inside WS_G (consumed before k_fusedT writes G):
#define WS_H      0x260000u  // f32[4*16*64]   (16 KB) read by k_small2
#define WS_XPART  0x264000u  // f32[64*64]     (16 KB) read by k_batchstats
#define WS_S2     0x268000u  // f32[4*64]      (1 KB)  read by k_small2

__device__ __forceinline__ float bf2f(u16 u){ return __uint_as_float(((u32)u) << 16); }
__device__ __forceinline__ u16 f2bf(float f){
    u32 x = __float_as_uint(f);
    x += 0x7fffu + ((x >> 16) & 1u);
    return (u16)(x >> 16);
}

// ---------------- K1: per-row stats of A (moc, dp) + X column-sum partials ----------------
__global__ __launch_bounds__(256) void k_rowstats(const float* __restrict__ A,
                                                  const float* __restrict__ X,
                                                  float* __restrict__ moc,
                                                  float* __restrict__ dpv,
                                                  float* __restrict__ Xpart)
{
    if (blockIdx.x < NB*CI*NN/4) {
        int wave = threadIdx.x >> 6, lane = threadIdx.x & 63;
        int row = blockIdx.x * 4 + wave;           // (b*8+c)*1024 + i
        int i = row & (NN - 1);
        const float* rp = A + (size_t)row * NN;
        f32x4 v0 = *(const f32x4*)(rp + lane * 16);
        f32x4 v1 = *(const f32x4*)(rp + lane * 16 + 4);
        f32x4 v2 = *(const f32x4*)(rp + lane * 16 + 8);
        f32x4 v3 = *(const f32x4*)(rp + lane * 16 + 12);
        float s = 0.f;
        #pragma unroll
        for (int e = 0; e < 4; e++) s += v0[e] + v1[e] + v2[e] + v3[e];
        #pragma unroll
        for (int off = 32; off; off >>= 1) s += __shfl_down(s, off);
        if (lane == 0) {
            moc[row] = s * (1.f / NN);
            dpv[row] = rp[i];
        }
    } else {
        // X column-sum partials: 64 blocks, each sums 64 rows of X[b]
        int idx = blockIdx.x - NB*CI*NN/4;   // 0..63
        int b = idx >> 4, seg = idx & 15;
        int g = threadIdx.x >> 6, x = threadIdx.x & 63;
        __shared__ float red[4][64];
        float s = 0.f;
        #pragma unroll
        for (int k = 0; k < 16; k++) {
            int i = seg*64 + g*16 + k;
            s += X[((size_t)b*NN + i)*XD + x];
        }
        red[g][x] = s;
        __syncthreads();
        if (threadIdx.x < 64)
            Xpart[idx*64 + threadIdx.x] =
                red[0][threadIdx.x]+red[1][threadIdx.x]+red[2][threadIdx.x]+red[3][threadIdx.x];
    }
}

// ---------------- K2: per-batch constants ----------------
__global__ __launch_bounds__(256) void k_batchstats(
    const float* __restrict__ Xpart,
    const float* __restrict__ moc, const float* __restrict__ dpv,
    const float* __restrict__ AW2, const float* __restrict__ AW4, const float* __restrict__ AW7,
    const float* __restrict__ Abias,
    const float* __restrict__ X1W2, const float* __restrict__ X1W5, const float* __restrict__ X1W6,
    const float* __restrict__ X1b,
    const float* __restrict__ X2W2, const float* __restrict__ X2W5, const float* __restrict__ X2W6,
    const float* __restrict__ X2b,
    float* __restrict__ constA_o, float* __restrict__ cx1_o, float* __restrict__ cx2_o)
{
    int b = blockIdx.x, tid = threadIdx.x;
    __shared__ float sdp[8][32], smoc[8][32];
    __shared__ float mdp_s[8], mall_s[8], mx_s[64];
    {
        int c = tid >> 5, rr = tid & 31;
        float pd = 0.f, pm = 0.f;
        for (int i = rr; i < NN; i += 32) {
            pd += dpv[(b*CI + c)*NN + i];
            pm += moc[(b*CI + c)*NN + i];
        }
        sdp[c][rr] = pd; smoc[c][rr] = pm;
    }
    if (tid < 64) {
        float px = 0.f;
        #pragma unroll
        for (int s = 0; s < 16; s++) px += Xpart[(b*16 + s)*64 + tid];
        mx_s[tid] = px * (1.f/NN);
    }
    __syncthreads();
    if (tid < 8) {
        float sd = 0.f, sm = 0.f;
        for (int k = 0; k < 32; k++) { sd += sdp[tid][k]; sm += smoc[tid][k]; }
        mdp_s[tid] = sd * (1.f/NN); mall_s[tid] = sm * (1.f/NN);
    }
    __syncthreads();
    if (tid < SO) {
        float v = Abias[tid];
        #pragma unroll
        for (int c = 0; c < 8; c++)
            v += mall_s[c]*AW2[c*SO+tid] + mdp_s[c]*AW4[c*SO+tid];
        for (int x = 0; x < 64; x++) v += mx_s[x]*AW7[x*SO+tid];
        constA_o[b*SO + tid] = v;
    }
    if (tid < 64) {
        float v1 = X1b[tid], v2 = X2b[tid];
        for (int x = 0; x < 64; x++) {
            float m = mx_s[x];
            v1 += m*X1W2[x*64+tid];
            v2 += m*X2W2[x*64+tid];
        }
        #pragma unroll
        for (int c = 0; c < 8; c++) {
            v1 += mall_s[c]*X1W6[c*64+tid] + mdp_s[c]*X1W5[c*64+tid];
            v2 += mall_s[c]*X2W6[c*64+tid] + mdp_s[c]*X2W5[c*64+tid];
        }
        cx1_o[b*64+tid] = v1; cx2_o[b*64+tid] = v2;
    }
}

// ---------------- K3: per-node row quantities: pairA, X1t, X2t^T ----------------
__global__ __launch_bounds__(256) void k_rows(const float* __restrict__ X,
    const float* __restrict__ moc, const float* __restrict__ dpv,
    const float* __restrict__ AW3, const float* __restrict__ AW5, const float* __restrict__ AW6,
    const float* __restrict__ X1W1, const float* __restrict__ X1W3, const float* __restrict__ X1W4,
    const float* __restrict__ X2W1, const float* __restrict__ X2W3, const float* __restrict__ X2W4,
    const float* __restrict__ cx1, const float* __restrict__ cx2,
    float* __restrict__ X1t, u16* __restrict__ X2tT,
    float* __restrict__ pairA, float* __restrict__ pairAT)
{
    int wave = threadIdx.x >> 6, u = threadIdx.x & 63;
    int r = blockIdx.x * 4 + wave;
    int b = r >> 10, i = r & (NN - 1);
    float xv = X[(size_t)r*XD + u];
    float a1 = cx1[b*XD + u], a2 = cx2[b*XD + u];
    int s = u & 15;
    float pa = 0.f;
    for (int x = 0; x < XD; x++) {
        float xx = __shfl(xv, x);
        a1 += xx * X1W1[x*XD + u];
        a2 += xx * X2W1[x*XD + u];
        pa += xx * AW6[x*SO + s];
    }
    #pragma unroll
    for (int c = 0; c < CI; c++) {
        float mv = moc[(b*CI + c)*NN + i];
        float dv = dpv[(b*CI + c)*NN + i];
        a1 += mv*X1W3[c*XD+u] + dv*X1W4[c*XD+u];
        a2 += mv*X2W3[c*XD+u] + dv*X2W4[c*XD+u];
        pa += mv*AW3[c*SO+s] + dv*AW5[c*SO+s];
    }
    X1t[(size_t)r*XD + u] = a1;
    X2tT[((size_t)b*XD + u)*NN + i] = f2bf(a2);
    if (u < SO) {
        pairA[(size_t)r*SO + u] = pa;
        pairAT[((size_t)b*SO + u)*NN + i] = pa;
    }
}

// ---------------- K4a: H[b,s,t] = sum_i pairAT[b,s,i]*X2t[b,t,i]; s2[b,t] = sum_i X2t[b,t,i] ----------------
__global__ __launch_bounds__(256) void k_H(const float* __restrict__ pairAT,
                                           const u16* __restrict__ X2tT,
                                           float* __restrict__ H, float* __restrict__ s2)
{
    __shared__ float red[4][64];
    int tid = threadIdx.x;
    int t = tid & 63, g = tid >> 6;
    if (blockIdx.x < 64) {
        int b = blockIdx.x >> 4, s = blockIdx.x & 15;
        const u16* x2 = X2tT + ((size_t)(b*XD) + t)*NN;
        const float* par = pairAT + ((size_t)(b*SO) + s)*NN;
        float h = 0.f;
        for (int i = g*256; i < (g+1)*256; i += 8) {
            bf16x8 v = __builtin_bit_cast(bf16x8, *(const uint4*)(x2 + i));
            f32x4 p0 = *(const f32x4*)(par + i);
            f32x4 p1 = *(const f32x4*)(par + i + 4);
            #pragma unroll
            for (int e = 0; e < 4; e++)
                h += p0[e]*bf2f((u16)v[e]) + p1[e]*bf2f((u16)v[e+4]);
        }
        red[g][t] = h;
        __syncthreads();
        if (tid < 64)
            H[((size_t)(b*SO) + s)*64 + tid] = red[0][tid]+red[1][tid]+red[2][tid]+red[3][tid];
    } else {
        int b = blockIdx.x - 64;
        const u16* x2 = X2tT + ((size_t)(b*XD) + t)*NN;
        float p = 0.f;
        for (int i = g*256; i < (g+1)*256; i += 8) {
            bf16x8 v = __builtin_bit_cast(bf16x8, *(const uint4*)(x2 + i));
            #pragma unroll
            for (int e = 0; e < 8; e++) p += bf2f((u16)v[e]);
        }
        red[g][t] = p;
        __syncthreads();
        if (tid < 64)
            s2[b*64 + tid] = red[0][tid]+red[1][tid]+red[2][tid]+red[3][tid];
    }
}

// ---------------- K4b: K1, C2 (blocks 0-3) + fused weights WGT (blocks 4-131) ----------------
__global__ __launch_bounds__(256) void k_small2(const float* __restrict__ Wo, const float* __restrict__ AW1,
    const float* __restrict__ constA, const float* __restrict__ H, const float* __restrict__ s2,
    float* __restrict__ K1, float* __restrict__ C2, u16* __restrict__ WGT)
{
    int tid = threadIdx.x;
    if (blockIdx.x < 4) {
        int b = blockIdx.x;
        __shared__ float ls[4][64];
        int t = tid & 63, g = tid >> 6;
        const float* s2b = s2 + b*64;
        float pc = 0.f;
        #pragma unroll
        for (int si = 0; si < 4; si++) {
            int s = g*4 + si;
            float ca = constA[b*SO + s];
            const float* Hs = H + ((size_t)(b*SO) + s)*64;
            float v = 0.f;
            for (int tt = 0; tt < 64; tt++) {
                float w = Wo[(s*64+tt)*64 + t];
                v  += s2b[tt] * w;
                pc += (Hs[tt] + ca*s2b[tt]) * w;
            }
            K1[((size_t)(b*SO) + s)*XD + t] = v;
        }
        ls[g][t] = pc;
        __syncthreads();
        if (tid < 64) C2[b*XD + tid] = (ls[0][tid]+ls[1][tid]+ls[2][tid]+ls[3][tid]) * (1.f/NN);
    } else {
        int o = (blockIdx.x - 4)*256 + tid;     // 0..32767
        int u = o >> 9;
        int k = o & 511;
        int c = k >> 6, t = k & 63;
        float v = 0.f;
        #pragma unroll
        for (int s = 0; s < SO; s++) v += AW1[c*SO+s] * Wo[(s*64+t)*64 + u];
        WGT[(size_t)u*512 + k] = f2bf(v);
    }
}

// ---------------- K5: fused At writer + G MFMA, t/s-split for 2 blocks/CU ----------------
// Grid: 512 blocks = (b, i-tile of 16, th). 512 threads = 8 waves = (jq in [0,4), nt2 in [0,2)).
// Block th owns: G t-half [th*32, th*32+32) (disjoint writes, bf16 to global),
//                At s-half [th*8, th*8+8) further split by nt2 (4 s per wave).
// Each wave streams A[i-tile, its j-quarter] once; fp32 path -> out0, bf16 path -> MFMA.
// G reduced over the 4 j-quarters via LDS. __launch_bounds__(512,4) caps VGPR at 128
// so 2 blocks (16 waves) fit per CU.
__global__ __launch_bounds__(512, 4) void k_fusedT(
    const float* __restrict__ A, const u16* __restrict__ X2tT,
    const float* __restrict__ AW1,
    const float* __restrict__ pairA, const float* __restrict__ pairAT,
    const float* __restrict__ constA,
    u16* __restrict__ G, float* __restrict__ out0)
{
    __shared__ float W1s[CI][SO];
    __shared__ __align__(16) float Gsh[2][3][CI][64][4];   // 48 KB: [nt2][jq-1][c][lane][reg]

    int tid = threadIdx.x;
    int wave = tid >> 6, lane = tid & 63;
    int lr = lane & 15, lq = lane >> 4;
    int nt2 = wave & 1, jq = wave >> 1;
    int b  = blockIdx.x >> 7;
    int r7 = blockIdx.x & 127;
    int i0 = (r7 >> 1) * 16;
    int th = r7 & 1;
    int t16 = th*32 + nt2*16;
    int s4r = th*8 + nt2*4;

    if (tid < CI*SO) W1s[tid >> 4][tid & 15] = AW1[tid];

    float rc[4];
    {
        f32x4 t4 = *(const f32x4*)(pairA + ((size_t)(b*NN) + i0 + lr)*SO + s4r);
        const float* ca = constA + b*SO + s4r;
        #pragma unroll
        for (int s = 0; s < 4; s++) rc[s] = t4[s] + ca[s];
    }
    __syncthreads();   // W1s ready

    const float* Ab = A + ((size_t)(b*CI))*NN*NN + (size_t)(i0 + lr)*NN;
    const u16*  Xb = X2tT + ((size_t)(b*XD) + t16 + lr)*NN;

    f32x4 acc[CI];
    #pragma unroll
    for (int c = 0; c < CI; c++) acc[c] = (f32x4){0.f,0.f,0.f,0.f};

    for (int st = 0; st < 8; st++) {
        int j0 = jq*256 + st*32 + lq*8;
        f32x4 a0[CI], a1[CI];
        #pragma unroll
        for (int c = 0; c < CI; c++) {
            const float* ar = Ab + (size_t)c*NN*NN + j0;
            a0[c] = *(const f32x4*)ar;
            a1[c] = *(const f32x4*)(ar + 4);
        }
        bf16x8 bfr = __builtin_bit_cast(bf16x8, *(const uint4*)(Xb + j0));
        // At: this wave owns s in [s4r, s4r+4), rows i0+lr, cols j0..j0+7
        #pragma unroll
        for (int ss = 0; ss < 4; ss++) {
            int s = s4r + ss;
            const float* pt = pairAT + ((size_t)(b*SO) + s)*NN + j0;
            f32x4 p0 = *(const f32x4*)pt;
            f32x4 p1 = *(const f32x4*)(pt + 4);
            f32x4 o0, o1;
            #pragma unroll
            for (int e = 0; e < 4; e++) { o0[e] = rc[ss] + p0[e]; o1[e] = rc[ss] + p1[e]; }
            #pragma unroll
            for (int c = 0; c < CI; c++) {
                float wv = W1s[c][s];
                #pragma unroll
                for (int e = 0; e < 4; e++) { o0[e] += a0[c][e]*wv; o1[e] += a1[c][e]*wv; }
            }
            float* op = out0 + (((size_t)(b*SO + s))*NN + i0 + lr)*NN + j0;
            *(f32x4*)op = o0;
            *(f32x4*)(op + 4) = o1;
        }
        // G MFMA: bf16 fragments from the same registers
        #pragma unroll
        for (int c = 0; c < CI; c++) {
            bf16x8 af;
            #pragma unroll
            for (int e = 0; e < 4; e++) { af[e] = (short)f2bf(a0[c][e]); af[e+4] = (short)f2bf(a1[c][e]); }
            acc[c] = __builtin_amdgcn_mfma_f32_16x16x32_bf16(af, bfr, acc[c], 0, 0, 0);
        }
    }

    // ---- reduce the 4 j-quarters, write bf16 G (disjoint t-half per block) ----
    if (jq) {
        #pragma unroll
        for (int c = 0; c < CI; c++)
            *(f32x4*)&Gsh[nt2][jq-1][c][lane][0] = acc[c];
    }
    __syncthreads();
    if (jq == 0) {
        #pragma unroll
        for (int c = 0; c < CI; c++) {
            f32x4 g = acc[c];
            #pragma unroll
            for (int p = 0; p < 3; p++) {
                f32x4 o = *(const f32x4*)&Gsh[nt2][p][c][lane][0];
                #pragma unroll
                for (int e = 0; e < 4; e++) g[e] += o[e];
            }
            #pragma unroll
            for (int reg = 0; reg < 4; reg++)
                G[((size_t)(b*CI + c)*NN + i0 + lq*4 + reg)*XD + t16 + lr] = f2bf(g[reg]);
        }
    }
}

// ---------------- K6: out1[b,i,u] = (1/n)(G.WG + pairA.K1) + C2 + ob + X1t ----------------
__global__ __launch_bounds__(256) void k_out(const u16* __restrict__ G, const u16* __restrict__ WGT,
    const float* __restrict__ pairA, const float* __restrict__ K1, const float* __restrict__ C2,
    const float* __restrict__ X1t, const float* __restrict__ outb, float* __restrict__ out1)
{
    int tid = threadIdx.x, wave = tid >> 6, lane = tid & 63;
    int lr = lane & 15, lq = lane >> 4;
    int rbase = blockIdx.x * 32;        // 128 blocks, one 32-row tile each
    int b = rbase >> 10;
    int ib = rbase & (NN - 1);
    int nt = wave;                       // one t-16 quarter per wave
    f32x4 acc[2];
    acc[0] = (f32x4){0.f,0.f,0.f,0.f};
    acc[1] = (f32x4){0.f,0.f,0.f,0.f};
    for (int k0 = 0; k0 < 512; k0 += 32) {
        int c = k0 >> 6;
        int tp = (k0 & 63) + lq*8;
        bf16x8 af0 = __builtin_bit_cast(bf16x8,
            *(const uint4*)(G + ((size_t)(b*CI + c)*NN + ib + lr)*XD + tp));
        bf16x8 af1 = __builtin_bit_cast(bf16x8,
            *(const uint4*)(G + ((size_t)(b*CI + c)*NN + ib + 16 + lr)*XD + tp));
        bf16x8 bfr = __builtin_bit_cast(bf16x8,
            *(const uint4*)(WGT + (size_t)(nt*16 + lr)*512 + k0 + lq*8));
        acc[0] = __builtin_amdgcn_mfma_f32_16x16x32_bf16(af0, bfr, acc[0], 0, 0, 0);
        acc[1] = __builtin_amdgcn_mfma_f32_16x16x32_bf16(af1, bfr, acc[1], 0, 0, 0);
    }
    int u = nt*16 + lr;
    float k1c[SO];
    #pragma unroll
    for (int s = 0; s < SO; s++) k1c[s] = K1[((size_t)(b*SO) + s)*XD + u];
    float cb = C2[b*XD + u] + outb[u];
    #pragma unroll
    for (int mt = 0; mt < 2; mt++)
        #pragma unroll
        for (int reg = 0; reg < 4; reg++) {
            int ii = ib + mt*16 + lq*4 + reg;
            const float* pa = pairA + ((size_t)(b*NN) + ii)*SO;
            float s16 = 0.f;
            #pragma unroll
            for (int s = 0; s < SO; s++) s16 += pa[s] * k1c[s];
            out1[((size_t)(b*NN) + ii)*XD + u] =
                (acc[mt][reg] + s16) * (1.f/NN) + cb
                + X1t[((size_t)(b*NN) + ii)*XD + u];
        }
}

extern "C" void kernel_launch(void* const* d_in, const int* in_sizes, int n_in,
                              void* d_out, int out_size, void* d_ws, size_t ws_size,
                              hipStream_t stream)
{
    const float* A     = (const float*)d_in[0];
    const float* X     = (const float*)d_in[1];
    const float* AW1   = (const float*)d_in[2];
    const float* AW2   = (const float*)d_in[3];
    const float* AW3   = (const float*)d_in[4];
    const float* AW4   = (const float*)d_in[5];
    const float* AW5   = (const float*)d_in[6];
    const float* AW6   = (const float*)d_in[7];
    const float* AW7   = (const float*)d_in[8];
    const float* Abias = (const float*)d_in[9];
    const float* X1W1  = (const float*)d_in[10];
    const float* X1W2  = (const float*)d_in[11];
    const float* X1W3  = (const float*)d_in[12];
    const float* X1W4  = (const float*)d_in[13];
    const float* X1W5  = (const float*)d_in[14];
    const float* X1W6  = (const float*)d_in[15];
    const float* X1b   = (const float*)d_in[16];
    const float* X2W1  = (const float*)d_in[17];
    const float* X2W2  = (const float*)d_in[18];
    const float* X2W3  = (const float*)d_in[19];
    const float* X2W4  = (const float*)d_in[20];
    const float* X2W5  = (const float*)d_in[21];
    const float* X2W6  = (const float*)d_in[22];
    const float* X2b   = (const float*)d_in[23];
    const float* Wo    = (const float*)d_in[24];
    const float* outb  = (const float*)d_in[25];

    char* ws = (char*)d_ws;
    float* moc    = (float*)(ws + WS_MOC);
    float* dpv    = (float*)(ws + WS_DP);
    float* constA = (float*)(ws + WS_CONSTA);
    float* cx1    = (float*)(ws + WS_CX1);
    float* cx2    = (float*)(ws + WS_CX2);
    float* K1     = (float*)(ws + WS_K1);
    float* C2     = (float*)(ws + WS_C2);
    float* pairA  = (float*)(ws + WS_PAIRA);
    float* pairAT = (float*)(ws + WS_PAIRAT);
    float* X1t    = (float*)(ws + WS_X1T);
    u16*   X2tT   = (u16*)(ws + WS_X2TT);
    u16*   WGT    = (u16*)(ws + WS_WGT);
    u16*   G      = (u16*)(ws + WS_G);
    float* H      = (float*)(ws + WS_H);
    float* Xpart  = (float*)(ws + WS_XPART);
    float* s2     = (float*)(ws + WS_S2);

    float* out0 = (float*)d_out;
    float* out1 = out0 + (size_t)NB*SO*NN*NN;

    k_rowstats<<<dim3(NB*CI*NN/4 + 64), dim3(256), 0, stream>>>(A, X, moc, dpv, Xpart);
    k_batchstats<<<dim3(NB), dim3(256), 0, stream>>>(Xpart, moc, dpv,
        AW2, AW4, AW7, Abias, X1W2, X1W5, X1W6, X1b, X2W2, X2W5, X2W6, X2b,
        constA, cx1, cx2);
    k_rows<<<dim3(NB*NN/4), dim3(256), 0, stream>>>(X, moc, dpv,
        AW3, AW5, AW6, X1W1, X1W3, X1W4, X2W1, X2W3, X2W4, cx1, cx2,
        X1t, X2tT, pairA, pairAT);
    k_H<<<dim3(68), dim3(256), 0, stream>>>(pairAT, X2tT, H, s2);
    k_small2<<<dim3(132), dim3(256), 0, stream>>>(Wo, AW1, constA, H, s2, K1, C2, WGT);
    k_fusedT<<<dim3(NB*(NN/16)*2), dim3(512), 0, stream>>>(A, X2tT, AW1,
        pairA, pairAT, constA, G, out0);
    k_out<<<dim3(NB*NN/32), dim3(256), 0, stream>>>(G, WGT, pairA, K1, C2, X1t, outb, out1);
}

// Round 3
// 562.645 us; speedup vs baseline: 1.4167x; 1.4167x over previous
//
#include <hip/hip_runtime.h>

// GNN_layer: N=4, A_IN=8, A_OUT=16, X=64, n=1024.
// Inputs: float32. Outputs: float32 (reference output dtype).
// Decomposition:
//   At[b,i,j,s] = Base + pairA[i,s] + pairA[j,s] + constA[s],  Base = sum_c A[b,c,i,j] W1[c,s]
//   einsum factors through G[b,c,i,t] = A[b,c] @ X2t (MFMA, A cast to bf16 in-reg).
// ROUND 3: revert the A-duplicating t-split (round-2 regression: A read 2x -> L3 thrash,
// FETCH 594 MB). Back to one block per 16-row i-tile (A read once, L3-resident), G in LDS,
// out1 epilogue fused. NEW: software-pipelined main loop (double-buffered A prefetch,
// static register names -- no runtime-indexed arrays) + nontemporal out0 stores so the
// 268 MB write stream does not evict A from L3. Pre-kernel parallelization from round 2 kept.

#define NB 4
#define CI 8
#define SO 16
#define XD 64
#define NN 1024

typedef unsigned short u16;
typedef unsigned int u32;
typedef float f32x4 __attribute__((ext_vector_type(4)));
typedef short bf16x8 __attribute__((ext_vector_type(8)));

// ---- workspace layout (bytes), total <= 0x660000 = 6.7 MB ----
#define WS_MOC    0x000000u  // f32[4*8*1024]
#define WS_DP     0x020000u  // f32[4*8*1024]
#define WS_CONSTA 0x043000u  // f32[4*16]
#define WS_CX1    0x044000u  // f32[4*64]
#define WS_CX2    0x045000u  // f32[4*64]
#define WS_K1     0x048000u  // f32[4*16*64]
#define WS_C2     0x04C000u  // f32[4*64]
#define WS_PAIRA  0x050000u  // f32[4*1024*16]
#define WS_PAIRAT 0x090000u  // f32[4*16*1024]
#define WS_X1T    0x0D0000u  // f32[4*1024*64]
#define WS_X2TT   0x1D0000u  // bf16[4*64*1024]
#define WS_WGT    0x250000u  // bf16[64*512]
// Scratch region (G no longer stored globally):
#define WS_H      0x260000u  // f32[4*16*64]   (16 KB)
#define WS_XPART  0x264000u  // f32[64*64]     (16 KB)
#define WS_S2     0x268000u  // f32[4*64]      (1 KB)

__device__ __forceinline__ float bf2f(u16 u){ return __uint_as_float(((u32)u) << 16); }
__device__ __forceinline__ u16 f2bf(float f){
    u32 x = __float_as_uint(f);
    x += 0x7fffu + ((x >> 16) & 1u);
    return (u16)(x >> 16);
}

// ---------------- K1: per-row stats of A (moc, dp) + X column-sum partials ----------------
__global__ __launch_bounds__(256) void k_rowstats(const float* __restrict__ A,
                                                  const float* __restrict__ X,
                                                  float* __restrict__ moc,
                                                  float* __restrict__ dpv,
                                                  float* __restrict__ Xpart)
{
    if (blockIdx.x < NB*CI*NN/4) {
        int wave = threadIdx.x >> 6, lane = threadIdx.x & 63;
        int row = blockIdx.x * 4 + wave;           // (b*8+c)*1024 + i
        int i = row & (NN - 1);
        const float* rp = A + (size_t)row * NN;
        f32x4 v0 = *(const f32x4*)(rp + lane * 16);
        f32x4 v1 = *(const f32x4*)(rp + lane * 16 + 4);
        f32x4 v2 = *(const f32x4*)(rp + lane * 16 + 8);
        f32x4 v3 = *(const f32x4*)(rp + lane * 16 + 12);
        float s = 0.f;
        #pragma unroll
        for (int e = 0; e < 4; e++) s += v0[e] + v1[e] + v2[e] + v3[e];
        #pragma unroll
        for (int off = 32; off; off >>= 1) s += __shfl_down(s, off);
        if (lane == 0) {
            moc[row] = s * (1.f / NN);
            dpv[row] = rp[i];
        }
    } else {
        // X column-sum partials: 64 blocks, each sums 64 rows of X[b]
        int idx = blockIdx.x - NB*CI*NN/4;   // 0..63
        int b = idx >> 4, seg = idx & 15;
        int g = threadIdx.x >> 6, x = threadIdx.x & 63;
        __shared__ float red[4][64];
        float s = 0.f;
        #pragma unroll
        for (int k = 0; k < 16; k++) {
            int i = seg*64 + g*16 + k;
            s += X[((size_t)b*NN + i)*XD + x];
        }
        red[g][x] = s;
        __syncthreads();
        if (threadIdx.x < 64)
            Xpart[idx*64 + threadIdx.x] =
                red[0][threadIdx.x]+red[1][threadIdx.x]+red[2][threadIdx.x]+red[3][threadIdx.x];
    }
}

// ---------------- K2: per-batch constants ----------------
__global__ __launch_bounds__(256) void k_batchstats(
    const float* __restrict__ Xpart,
    const float* __restrict__ moc, const float* __restrict__ dpv,
    const float* __restrict__ AW2, const float* __restrict__ AW4, const float* __restrict__ AW7,
    const float* __restrict__ Abias,
    const float* __restrict__ X1W2, const float* __restrict__ X1W5, const float* __restrict__ X1W6,
    const float* __restrict__ X1b,
    const float* __restrict__ X2W2, const float* __restrict__ X2W5, const float* __restrict__ X2W6,
    const float* __restrict__ X2b,
    float* __restrict__ constA_o, float* __restrict__ cx1_o, float* __restrict__ cx2_o)
{
    int b = blockIdx.x, tid = threadIdx.x;
    __shared__ float sdp[8][32], smoc[8][32];
    __shared__ float mdp_s[8], mall_s[8], mx_s[64];
    {
        int c = tid >> 5, rr = tid & 31;
        float pd = 0.f, pm = 0.f;
        for (int i = rr; i < NN; i += 32) {
            pd += dpv[(b*CI + c)*NN + i];
            pm += moc[(b*CI + c)*NN + i];
        }
        sdp[c][rr] = pd; smoc[c][rr] = pm;
    }
    if (tid < 64) {
        float px = 0.f;
        #pragma unroll
        for (int s = 0; s < 16; s++) px += Xpart[(b*16 + s)*64 + tid];
        mx_s[tid] = px * (1.f/NN);
    }
    __syncthreads();
    if (tid < 8) {
        float sd = 0.f, sm = 0.f;
        for (int k = 0; k < 32; k++) { sd += sdp[tid][k]; sm += smoc[tid][k]; }
        mdp_s[tid] = sd * (1.f/NN); mall_s[tid] = sm * (1.f/NN);
    }
    __syncthreads();
    if (tid < SO) {
        float v = Abias[tid];
        #pragma unroll
        for (int c = 0; c < 8; c++)
            v += mall_s[c]*AW2[c*SO+tid] + mdp_s[c]*AW4[c*SO+tid];
        for (int x = 0; x < 64; x++) v += mx_s[x]*AW7[x*SO+tid];
        constA_o[b*SO + tid] = v;
    }
    if (tid < 64) {
        float v1 = X1b[tid], v2 = X2b[tid];
        for (int x = 0; x < 64; x++) {
            float m = mx_s[x];
            v1 += m*X1W2[x*64+tid];
            v2 += m*X2W2[x*64+tid];
        }
        #pragma unroll
        for (int c = 0; c < 8; c++) {
            v1 += mall_s[c]*X1W6[c*64+tid] + mdp_s[c]*X1W5[c*64+tid];
            v2 += mall_s[c]*X2W6[c*64+tid] + mdp_s[c]*X2W5[c*64+tid];
        }
        cx1_o[b*64+tid] = v1; cx2_o[b*64+tid] = v2;
    }
}

// ---------------- K3: per-node row quantities: pairA, X1t, X2t^T ----------------
__global__ __launch_bounds__(256) void k_rows(const float* __restrict__ X,
    const float* __restrict__ moc, const float* __restrict__ dpv,
    const float* __restrict__ AW3, const float* __restrict__ AW5, const float* __restrict__ AW6,
    const float* __restrict__ X1W1, const float* __restrict__ X1W3, const float* __restrict__ X1W4,
    const float* __restrict__ X2W1, const float* __restrict__ X2W3, const float* __restrict__ X2W4,
    const float* __restrict__ cx1, const float* __restrict__ cx2,
    float* __restrict__ X1t, u16* __restrict__ X2tT,
    float* __restrict__ pairA, float* __restrict__ pairAT)
{
    int wave = threadIdx.x >> 6, u = threadIdx.x & 63;
    int r = blockIdx.x * 4 + wave;
    int b = r >> 10, i = r & (NN - 1);
    float xv = X[(size_t)r*XD + u];
    float a1 = cx1[b*XD + u], a2 = cx2[b*XD + u];
    int s = u & 15;
    float pa = 0.f;
    for (int x = 0; x < XD; x++) {
        float xx = __shfl(xv, x);
        a1 += xx * X1W1[x*XD + u];
        a2 += xx * X2W1[x*XD + u];
        pa += xx * AW6[x*SO + s];
    }
    #pragma unroll
    for (int c = 0; c < CI; c++) {
        float mv = moc[(b*CI + c)*NN + i];
        float dv = dpv[(b*CI + c)*NN + i];
        a1 += mv*X1W3[c*XD+u] + dv*X1W4[c*XD+u];
        a2 += mv*X2W3[c*XD+u] + dv*X2W4[c*XD+u];
        pa += mv*AW3[c*SO+s] + dv*AW5[c*SO+s];
    }
    X1t[(size_t)r*XD + u] = a1;
    X2tT[((size_t)b*XD + u)*NN + i] = f2bf(a2);
    if (u < SO) {
        pairA[(size_t)r*SO + u] = pa;
        pairAT[((size_t)b*SO + u)*NN + i] = pa;
    }
}

// ---------------- K4a: H[b,s,t] = sum_i pairAT[b,s,i]*X2t[b,t,i]; s2[b,t] = sum_i X2t[b,t,i] ----------------
__global__ __launch_bounds__(256) void k_H(const float* __restrict__ pairAT,
                                           const u16* __restrict__ X2tT,
                                           float* __restrict__ H, float* __restrict__ s2)
{
    __shared__ float red[4][64];
    int tid = threadIdx.x;
    int t = tid & 63, g = tid >> 6;
    if (blockIdx.x < 64) {
        int b = blockIdx.x >> 4, s = blockIdx.x & 15;
        const u16* x2 = X2tT + ((size_t)(b*XD) + t)*NN;
        const float* par = pairAT + ((size_t)(b*SO) + s)*NN;
        float h = 0.f;
        for (int i = g*256; i < (g+1)*256; i += 8) {
            bf16x8 v = __builtin_bit_cast(bf16x8, *(const uint4*)(x2 + i));
            f32x4 p0 = *(const f32x4*)(par + i);
            f32x4 p1 = *(const f32x4*)(par + i + 4);
            #pragma unroll
            for (int e = 0; e < 4; e++)
                h += p0[e]*bf2f((u16)v[e]) + p1[e]*bf2f((u16)v[e+4]);
        }
        red[g][t] = h;
        __syncthreads();
        if (tid < 64)
            H[((size_t)(b*SO) + s)*64 + tid] = red[0][tid]+red[1][tid]+red[2][tid]+red[3][tid];
    } else {
        int b = blockIdx.x - 64;
        const u16* x2 = X2tT + ((size_t)(b*XD) + t)*NN;
        float p = 0.f;
        for (int i = g*256; i < (g+1)*256; i += 8) {
            bf16x8 v = __builtin_bit_cast(bf16x8, *(const uint4*)(x2 + i));
            #pragma unroll
            for (int e = 0; e < 8; e++) p += bf2f((u16)v[e]);
        }
        red[g][t] = p;
        __syncthreads();
        if (tid < 64)
            s2[b*64 + tid] = red[0][tid]+red[1][tid]+red[2][tid]+red[3][tid];
    }
}

// ---------------- K4b: K1, C2 (blocks 0-3) + fused weights WGT (blocks 4-131) ----------------
__global__ __launch_bounds__(256) void k_small2(const float* __restrict__ Wo, const float* __restrict__ AW1,
    const float* __restrict__ constA, const float* __restrict__ H, const float* __restrict__ s2,
    float* __restrict__ K1, float* __restrict__ C2, u16* __restrict__ WGT)
{
    int tid = threadIdx.x;
    if (blockIdx.x < 4) {
        int b = blockIdx.x;
        __shared__ float ls[4][64];
        int t = tid & 63, g = tid >> 6;
        const float* s2b = s2 + b*64;
        float pc = 0.f;
        #pragma unroll
        for (int si = 0; si < 4; si++) {
            int s = g*4 + si;
            float ca = constA[b*SO + s];
            const float* Hs = H + ((size_t)(b*SO) + s)*64;
            float v = 0.f;
            for (int tt = 0; tt < 64; tt++) {
                float w = Wo[(s*64+tt)*64 + t];
                v  += s2b[tt] * w;
                pc += (Hs[tt] + ca*s2b[tt]) * w;
            }
            K1[((size_t)(b*SO) + s)*XD + t] = v;
        }
        ls[g][t] = pc;
        __syncthreads();
        if (tid < 64) C2[b*XD + tid] = (ls[0][tid]+ls[1][tid]+ls[2][tid]+ls[3][tid]) * (1.f/NN);
    } else {
        int o = (blockIdx.x - 4)*256 + tid;     // 0..32767
        int u = o >> 9;
        int k = o & 511;
        int c = k >> 6, t = k & 63;
        float v = 0.f;
        #pragma unroll
        for (int s = 0; s < SO; s++) v += AW1[c*SO+s] * Wo[(s*64+t)*64 + u];
        WGT[(size_t)u*512 + k] = f2bf(v);
    }
}

// ---------------- K5: fused At writer + G MFMA + out1 epilogue (pipelined) ----------------
// Grid: 256 blocks = (b, i-tile of 16 rows). 512 threads = 8 waves.
// wave = (nt = wave&3: t/u/s quarter, jh = wave>>2: j half).
// Main loop software-pipelined: A loads for step st+1 issue into the alternate register
// buffer (static names aA*/aB*, rule-#20 safe) while step st computes At (fp32, NT store)
// and the G MFMA (bf16). Epilogue: reduce G j-halves via LDS, cast to bf16, MFMA vs WGT.
#define LOAD_STEP(ST, A0, A1, BF) { \
    int j0_ = jh*512 + (ST)*32 + lq*8; \
    _Pragma("unroll") \
    for (int c = 0; c < CI; c++) { \
        const float* ar_ = Ab + (size_t)c*NN*NN + j0_; \
        A0[c] = *(const f32x4*)ar_; \
        A1[c] = *(const f32x4*)(ar_ + 4); \
    } \
    BF = __builtin_bit_cast(bf16x8, *(const uint4*)(Xb + j0_)); \
}

#define COMP_STEP(ST, A0, A1, BF) { \
    int j0_ = jh*512 + (ST)*32 + lq*8; \
    _Pragma("unroll") \
    for (int s = 0; s < 4; s++) { \
        const float* pt_ = pairAT + ((size_t)(b*SO) + s4 + s)*NN + j0_; \
        f32x4 p0 = *(const f32x4*)pt_; \
        f32x4 p1 = *(const f32x4*)(pt_ + 4); \
        f32x4 o0, o1; \
        _Pragma("unroll") \
        for (int e = 0; e < 4; e++) { o0[e] = rc[s] + p0[e]; o1[e] = rc[s] + p1[e]; } \
        _Pragma("unroll") \
        for (int c = 0; c < CI; c++) { \
            float wv = W1s[c][s4 + s]; \
            _Pragma("unroll") \
            for (int e = 0; e < 4; e++) { o0[e] += A0[c][e]*wv; o1[e] += A1[c][e]*wv; } \
        } \
        float* op_ = out0 + (((size_t)(b*SO + s4 + s))*NN + i0 + lr)*NN + j0_; \
        __builtin_nontemporal_store(o0, (f32x4*)op_); \
        __builtin_nontemporal_store(o1, (f32x4*)(op_ + 4)); \
    } \
    _Pragma("unroll") \
    for (int c = 0; c < CI; c++) { \
        bf16x8 af; \
        _Pragma("unroll") \
        for (int e = 0; e < 4; e++) { af[e] = (short)f2bf(A0[c][e]); af[e+4] = (short)f2bf(A1[c][e]); } \
        acc[c] = __builtin_amdgcn_mfma_f32_16x16x32_bf16(af, BF, acc[c], 0, 0, 0); \
    } \
}

__global__ __launch_bounds__(512, 2) void k_fused(
    const float* __restrict__ A, const u16* __restrict__ X2tT,
    const float* __restrict__ AW1,
    const float* __restrict__ pairA, const float* __restrict__ pairAT,
    const float* __restrict__ constA,
    const u16* __restrict__ WGT, const float* __restrict__ K1,
    const float* __restrict__ C2, const float* __restrict__ X1t,
    const float* __restrict__ outb,
    float* __restrict__ out0, float* __restrict__ out1)
{
    __shared__ float W1s[CI][SO];
    __shared__ __align__(16) float Gsh[4][CI][64][4];   // 32 KB: [nt][c][lane][reg]
    __shared__ __align__(16) u16 Gb[16][520];           // 16.6 KB, +8 col pad

    int tid = threadIdx.x;
    int wave = tid >> 6, lane = tid & 63;
    int lr = lane & 15, lq = lane >> 4;
    int nt = wave & 3, jh = wave >> 2;
    int b = blockIdx.x >> 6;
    int i0 = (blockIdx.x & 63) * 16;
    int s4 = nt * 4;

    if (tid < CI*SO) W1s[tid >> 4][tid & 15] = AW1[tid];

    float rc[4];
    {
        f32x4 t = *(const f32x4*)(pairA + ((size_t)(b*NN) + i0 + lr)*SO + s4);
        const float* ca = constA + b*SO + s4;
        #pragma unroll
        for (int s = 0; s < 4; s++) rc[s] = t[s] + ca[s];
    }
    __syncthreads();   // W1s ready

    const float* Ab = A + ((size_t)b*CI)*NN*NN + (size_t)(i0 + lr)*NN;
    const u16*  Xb = X2tT + ((size_t)(b*XD) + nt*16 + lr)*NN;

    f32x4 acc[CI];
    #pragma unroll
    for (int c = 0; c < CI; c++) acc[c] = (f32x4){0.f,0.f,0.f,0.f};

    // Software pipeline over the 16 j-steps: buffers A (even steps) / B (odd steps).
    f32x4 aA0[CI], aA1[CI], aB0[CI], aB1[CI];
    bf16x8 bfA, bfB;
    LOAD_STEP(0, aA0, aA1, bfA);
    for (int st2 = 0; st2 < 8; st2++) {
        LOAD_STEP(st2*2 + 1, aB0, aB1, bfB);
        COMP_STEP(st2*2, aA0, aA1, bfA);
        if (st2 < 7) LOAD_STEP(st2*2 + 2, aA0, aA1, bfA);
        COMP_STEP(st2*2 + 1, aB0, aB1, bfB);
    }

    // ---- reduce j-halves, build bf16 G tile in LDS ----
    if (jh == 1) {
        #pragma unroll
        for (int c = 0; c < CI; c++)
            *(f32x4*)&Gsh[nt][c][lane][0] = acc[c];
    }
    __syncthreads();
    if (jh == 0) {
        #pragma unroll
        for (int c = 0; c < CI; c++) {
            f32x4 g = *(const f32x4*)&Gsh[nt][c][lane][0];
            #pragma unroll
            for (int reg = 0; reg < 4; reg++)
                Gb[lq*4 + reg][c*64 + nt*16 + lr] = f2bf(acc[c][reg] + g[reg]);
        }
    }
    __syncthreads();

    // ---- out1 epilogue (jh==0 waves; 16 rows x 64 u, K=512) ----
    if (jh == 0) {
        f32x4 acc1 = (f32x4){0.f,0.f,0.f,0.f};
        #pragma unroll
        for (int k0 = 0; k0 < 512; k0 += 32) {
            bf16x8 ga = __builtin_bit_cast(bf16x8, *(const uint4*)&Gb[lr][k0 + lq*8]);
            bf16x8 wb = __builtin_bit_cast(bf16x8,
                *(const uint4*)(WGT + (size_t)(nt*16 + lr)*512 + k0 + lq*8));
            acc1 = __builtin_amdgcn_mfma_f32_16x16x32_bf16(ga, wb, acc1, 0, 0, 0);
        }
        int u = nt*16 + lr;
        float k1c[SO];
        #pragma unroll
        for (int s = 0; s < SO; s++) k1c[s] = K1[((size_t)(b*SO) + s)*XD + u];
        float cb = C2[b*XD + u] + outb[u];
        #pragma unroll
        for (int reg = 0; reg < 4; reg++) {
            int ii = i0 + lq*4 + reg;
            const float* pa = pairA + ((size_t)(b*NN) + ii)*SO;
            float s16 = 0.f;
            #pragma unroll
            for (int s = 0; s < SO; s++) s16 += pa[s] * k1c[s];
            out1[((size_t)(b*NN) + ii)*XD + u] =
                (acc1[reg] + s16) * (1.f/NN) + cb
                + X1t[((size_t)(b*NN) + ii)*XD + u];
        }
    }
}

extern "C" void kernel_launch(void* const* d_in, const int* in_sizes, int n_in,
                              void* d_out, int out_size, void* d_ws, size_t ws_size,
                              hipStream_t stream)
{
    const float* A     = (const float*)d_in[0];
    const float* X     = (const float*)d_in[1];
    const float* AW1   = (const float*)d_in[2];
    const float* AW2   = (const float*)d_in[3];
    const float* AW3   = (const float*)d_in[4];
    const float* AW4   = (const float*)d_in[5];
    const float* AW5   = (const float*)d_in[6];
    const float* AW6   = (const float*)d_in[7];
    const float* AW7   = (const float*)d_in[8];
    const float* Abias = (const float*)d_in[9];
    const float* X1W1  = (const float*)d_in[10];
    const float* X1W2  = (const float*)d_in[11];
    const float* X1W3  = (const float*)d_in[12];
    const float* X1W4  = (const float*)d_in[13];
    const float* X1W5  = (const float*)d_in[14];
    const float* X1W6  = (const float*)d_in[15];
    const float* X1b   = (const float*)d_in[16];
    const float* X2W1  = (const float*)d_in[17];
    const float* X2W2  = (const float*)d_in[18];
    const float* X2W3  = (const float*)d_in[19];
    const float* X2W4  = (const float*)d_in[20];
    const float* X2W5  = (const float*)d_in[21];
    const float* X2W6  = (const float*)d_in[22];
    const float* X2b   = (const float*)d_in[23];
    const float* Wo    = (const float*)d_in[24];
    const float* outb  = (const float*)d_in[25];

    char* ws = (char*)d_ws;
    float* moc    = (float*)(ws + WS_MOC);
    float* dpv    = (float*)(ws + WS_DP);
    float* constA = (float*)(ws + WS_CONSTA);
    float* cx1    = (float*)(ws + WS_CX1);
    float* cx2    = (float*)(ws + WS_CX2);
    float* K1     = (float*)(ws + WS_K1);
    float* C2     = (float*)(ws + WS_C2);
    float* pairA  = (float*)(ws + WS_PAIRA);
    float* pairAT = (float*)(ws + WS_PAIRAT);
    float* X1t    = (float*)(ws + WS_X1T);
    u16*   X2tT   = (u16*)(ws + WS_X2TT);
    u16*   WGT    = (u16*)(ws + WS_WGT);
    float* H      = (float*)(ws + WS_H);
    float* Xpart  = (float*)(ws + WS_XPART);
    float* s2     = (float*)(ws + WS_S2);

    float* out0 = (float*)d_out;
    float* out1 = out0 + (size_t)NB*SO*NN*NN;

    k_rowstats<<<dim3(NB*CI*NN/4 + 64), dim3(256), 0, stream>>>(A, X, moc, dpv, Xpart);
    k_batchstats<<<dim3(NB), dim3(256), 0, stream>>>(Xpart, moc, dpv,
        AW2, AW4, AW7, Abias, X1W2, X1W5, X1W6, X1b, X2W2, X2W5, X2W6, X2b,
        constA, cx1, cx2);
    k_rows<<<dim3(NB*NN/4), dim3(256), 0, stream>>>(X, moc, dpv,
        AW3, AW5, AW6, X1W1, X1W3, X1W4, X2W1, X2W3, X2W4, cx1, cx2,
        X1t, X2tT, pairA, pairAT);
    k_H<<<dim3(68), dim3(256), 0, stream>>>(pairAT, X2tT, H, s2);
    k_small2<<<dim3(132), dim3(256), 0, stream>>>(Wo, AW1, constA, H, s2, K1, C2, WGT);
    k_fused<<<dim3(NB*NN/16), dim3(512), 0, stream>>>(A, X2tT, AW1,
        pairA, pairAT, constA, WGT, K1, C2, X1t, outb, out0, out1);
}